// Round 10
// baseline (2559.754 us; speedup 1.0000x reference)
//
#include <hip/hip_runtime.h>
#include <math.h>

#define INPUT_DIM 256
#define N_CLASSES 100
#define MAX_DEPTH 12
#define N_NODES   4095
#define N_LEAVES  4096

#define TPB    512
#define NWAVE  8
#define PBLK   192                 // producer blocks (CUs)
#define CBLK   64                  // consumer blocks (CUs)
#define NBLK   (PBLK + CBLK)       // 256 = 1 block/CU, all co-resident
#define NPIPES (PBLK * NWAVE)      // 1536 producer pipelines
#define NCW    (CBLK * NWAVE)      // 512 consumer waves
#define PPCW   (NPIPES / NCW)      // 3 pipelines per consumer wave
#define RPW    8                   // rows per unit (500000 % 8 == 0)
#define TBUF   2                   // double buffer, prefetch distance 1
#define ROWP   260                 // padded row stride (1040 B)
#define NF4    (N_CLASSES / 4)     // 25 f32x4 per row
#define UF4    (RPW * NF4)         // 200 f32x4 per unit

#define WAITV0()  asm volatile("s_waitcnt vmcnt(0)" ::: "memory")
#define WAITV2()  asm volatile("s_waitcnt vmcnt(2)" ::: "memory")
#define WAITV8()  asm volatile("s_waitcnt vmcnt(8)" ::: "memory")
#define WAITV10() asm volatile("s_waitcnt vmcnt(10)" ::: "memory")
#define SCHEDB()  __builtin_amdgcn_sched_barrier(0)

typedef float f32x4 __attribute__((ext_vector_type(4)));

__device__ __forceinline__ void async_load16(const void* gsrc, void* ldst) {
    __builtin_amdgcn_global_load_lds(
        (const __attribute__((address_space(1))) unsigned int*)gsrc,
        (__attribute__((address_space(3))) unsigned int*)ldst, 16, 0, 0);
}

__device__ __forceinline__ int nk_of(int pipe, int nunits) {
    return (pipe < nunits) ? ((nunits - 1 - pipe) / NPIPES + 1) : 0;
}

// ---------------------------------------------------------------------------
// Kernel 1: row-softmax of leaf_probabilities [4096 x 100] -> tab
// ---------------------------------------------------------------------------
__global__ __launch_bounds__(64) void softmax_rows_kernel(
    const float* __restrict__ lp, float* __restrict__ tab) {
    const int row  = blockIdx.x;
    const int lane = threadIdx.x;
    const float* src = lp + (size_t)row * N_CLASSES;

    float v0 = src[lane];
    float v1 = (lane + 64 < N_CLASSES) ? src[lane + 64] : -INFINITY;

    float m = fmaxf(v0, v1);
    #pragma unroll
    for (int off = 32; off > 0; off >>= 1) m = fmaxf(m, __shfl_xor(m, off));

    float e0 = expf(v0 - m);
    float e1 = (lane + 64 < N_CLASSES) ? expf(v1 - m) : 0.0f;
    float s = e0 + e1;
    #pragma unroll
    for (int off = 32; off > 0; off >>= 1) s += __shfl_xor(s, off);

    const float inv = 1.0f / s;
    tab[(size_t)row * N_CLASSES + lane] = e0 * inv;
    if (lane + 64 < N_CLASSES)
        tab[(size_t)row * N_CLASSES + lane + 64] = e1 * inv;
}

// ---------------------------------------------------------------------------
// Kernel 2: CU-granularity producer/consumer.
// Producers (blocks 0..191): 8 barrier-free wave-pipelines each; unit = 8 rows
//   DMA'd global->LDS (global_load_lds_dwordx4), double-buffered, counted
//   per-wave vmcnt; 12-level LDS chain (children speculated); leaf u16 ->
//   global; per-unit release-atomic progress[pipe] = k+1 (AGENT scope).
//   Producers NEVER wait on consumers (leaf array is the full buffer).
// Consumers (blocks 192..255): 512 waves, 3 pipelines each; acquire-poll
//   progress, then per unit: 200 f32x4 = tab[leaf] gather (L2) + coalesced
//   nontemporal stores. One unit spans the whole wave -> latency hidden.
// All 256 blocks co-resident (153.6 KB LDS -> 1 block/CU) -> no deadlock.
// ---------------------------------------------------------------------------
__global__ __launch_bounds__(TPB) void tree_pc_kernel(
    const float* __restrict__ x,
    const float* __restrict__ split_features,
    const float* __restrict__ split_thresholds,
    const f32x4* __restrict__ tab4,
    unsigned short* leaf,
    unsigned int* progress,
    f32x4* __restrict__ out4,
    int batch, int nunits) {
    __shared__ float         s_rows[NWAVE][TBUF][RPW][ROWP];  // 133,120 B
    __shared__ float         s_thr[N_NODES];                  //  16,380 B
    __shared__ unsigned char s_feat[N_NODES + 1];             //   4,096 B

    const int tid  = threadIdx.x;
    const int wid  = tid >> 6;
    const int lane = tid & 63;

    // node table -> LDS (both roles; harmless for consumers)
    for (int i = tid; i < N_NODES; i += TPB) {
        s_thr[i] = split_thresholds[i];
        int f = (int)floorf(split_features[i]);
        s_feat[i] = (unsigned char)min(max(f, 0), INPUT_DIM - 1);
    }
    __syncthreads();

    if (blockIdx.x < PBLK) {
        // ========================= PRODUCER =========================
        const int pipe = blockIdx.x * NWAVE + wid;
        const int nk = nk_of(pipe, nunits);

        auto stage = [&](int k, int slot) {
            const long g = (long)pipe + (long)k * NPIPES;
            #pragma unroll
            for (int j = 0; j < RPW; ++j) {
                long r = g * RPW + j;
                if (r >= batch) r = batch - 1;      // valid dummy traffic
                const float* src = x + (size_t)r * INPUT_DIM + lane * 4;
                async_load16((const void*)src, (void*)&s_rows[wid][slot][j][0]);
            }
        };

        if (nk > 0) stage(0, 0);

        for (int k = 0; k < nk; ++k) {
            const bool more = (k + 1 < nk);
            if (more) stage(k + 1, (k + 1) & 1);    // prefetch next unit
            SCHEDB();
            // guarantee unit k's 8 DMAs retired, keep newer ops in flight:
            // newer = [st(k-1)+atomic(k-1)](2) + [DMA k+1](8 if more)
            if (k == 0) { if (more) WAITV8(); else WAITV0(); }
            else if (more) WAITV10(); else WAITV2();
            SCHEDB();

            int leafv = 0;
            if (lane < RPW) {
                const float* row = &s_rows[wid][k & 1][lane][0];
                float t = s_thr[0];
                int   f = s_feat[0];
                int   n = 0;
                #pragma unroll
                for (int d = 0; d < MAX_DEPTH; ++d) {
                    const int l = 2 * n + 1;
                    if (d < MAX_DEPTH - 1) {
                        const float tl = s_thr[l],  tr = s_thr[l + 1];
                        const int   fl = s_feat[l], fr = s_feat[l + 1];
                        const int go = row[f] > t ? 1 : 0;  // chain: 1 LDS gather/level
                        t = go ? tr : tl;
                        f = go ? fr : fl;
                        n = l + go;
                    } else {
                        n = l + (row[f] > t ? 1 : 0);
                    }
                }
                leafv = n - N_NODES;
            }

            const long rowbase = ((long)pipe + (long)k * NPIPES) * RPW;
            if (lane < RPW && rowbase + lane < batch)
                leaf[rowbase + lane] = (unsigned short)leafv;
            SCHEDB();
            if (lane == 0)
                __hip_atomic_store(&progress[pipe], (unsigned int)(k + 1),
                                   __ATOMIC_RELEASE, __HIP_MEMORY_SCOPE_AGENT);
            SCHEDB();
        }
        WAITV0();
    } else {
        // ========================= CONSUMER =========================
        const int cw    = (blockIdx.x - PBLK) * NWAVE + wid;  // [0,512)
        const int pbase = cw * PPCW;                          // 3 pipelines

        // per-lane (r,q) for the 4 output slots (static after full unroll)
        int rr[4], qq[4];
        #pragma unroll
        for (int t = 0; t < 4; ++t) {
            const int slot = lane + t * 64;
            rr[t] = slot / NF4;
            qq[t] = slot - rr[t] * NF4;
        }

        int done[PPCW], nks[PPCW];
        int rem = 0;
        #pragma unroll
        for (int i = 0; i < PPCW; ++i) {
            done[i] = 0;
            nks[i]  = nk_of(pbase + i, nunits);
            rem    += nks[i];
        }

        auto process = [&](int p, int k) {
            const long g = (long)p + (long)k * NPIPES;
            const long rowbase = g * RPW;
            const size_t b4 = (size_t)g * UF4;
            long ms = (batch - rowbase) * (long)NF4;
            const int maxs = ms > UF4 ? UF4 : (int)ms;
            #pragma unroll
            for (int t = 0; t < 4; ++t) {
                const int slot = lane + t * 64;
                if (slot < maxs) {
                    const int lf = leaf[rowbase + rr[t]];
                    f32x4 v = tab4[(size_t)lf * NF4 + qq[t]];
                    __builtin_nontemporal_store(v, &out4[b4 + slot]);
                }
            }
        };

        while (rem > 0) {
            bool prog = false;
            #pragma unroll
            for (int i = 0; i < PPCW; ++i) {
                if (done[i] >= nks[i]) continue;
                const int p = pbase + i;
                const int av = (int)__hip_atomic_load(
                    &progress[p], __ATOMIC_ACQUIRE, __HIP_MEMORY_SCOPE_AGENT);
                while (done[i] < av && done[i] < nks[i]) {
                    process(p, done[i]);
                    ++done[i]; --rem; prog = true;
                }
            }
            if (!prog) __builtin_amdgcn_s_sleep(2);
        }
    }
}

// ---------------------------------------------------------------------------
// Fallback (ws too small / tiny batch): fully fused, per-thread softmax.
// ---------------------------------------------------------------------------
__global__ __launch_bounds__(256) void fused_kernel(
    const float* __restrict__ x,
    const float* __restrict__ split_features,
    const float* __restrict__ split_thresholds,
    const float* __restrict__ lp,
    float* __restrict__ out, int batch) {
    __shared__ float2 s_nodes[N_NODES];
    for (int i = threadIdx.x; i < N_NODES; i += blockDim.x) {
        int f = (int)floorf(split_features[i]);
        f = min(max(f, 0), INPUT_DIM - 1);
        float2 n; n.x = split_thresholds[i]; n.y = __int_as_float(f);
        s_nodes[i] = n;
    }
    __syncthreads();

    const int b = blockIdx.x * blockDim.x + threadIdx.x;
    if (b >= batch) return;

    const float* row = x + (size_t)b * INPUT_DIM;
    int node = 0;
    #pragma unroll
    for (int d = 0; d < MAX_DEPTH; ++d) {
        const float2 n = s_nodes[node];
        const float val = row[__float_as_int(n.y)];
        node = 2 * node + 1 + (val > n.x ? 1 : 0);
    }
    const int leaf = node - N_NODES;

    const float* src = lp + (size_t)leaf * N_CLASSES;
    float m = -INFINITY;
    for (int c = 0; c < N_CLASSES; ++c) m = fmaxf(m, src[c]);
    float s = 0.0f;
    float e[N_CLASSES];
    for (int c = 0; c < N_CLASSES; ++c) { e[c] = expf(src[c] - m); s += e[c]; }
    const float inv = 1.0f / s;
    float* dst = out + (size_t)b * N_CLASSES;
    for (int c = 0; c < N_CLASSES; ++c) dst[c] = e[c] * inv;
}

// ---------------------------------------------------------------------------
extern "C" void kernel_launch(void* const* d_in, const int* in_sizes, int n_in,
                              void* d_out, int out_size, void* d_ws, size_t ws_size,
                              hipStream_t stream) {
    const float* x  = (const float*)d_in[0];
    const float* sf = (const float*)d_in[1];
    const float* st = (const float*)d_in[2];
    const float* lp = (const float*)d_in[3];
    float* out = (float*)d_out;

    const int batch = in_sizes[0] / INPUT_DIM;

    const size_t tab_bytes  = (size_t)N_LEAVES * N_CLASSES * sizeof(float); // 1.6384 MB
    const size_t leaf_bytes = ((size_t)batch * sizeof(unsigned short) + 3) & ~(size_t)3;
    const size_t prog_bytes = (size_t)NPIPES * sizeof(unsigned int);        // 6144 B
    const size_t need = tab_bytes + leaf_bytes + prog_bytes;

    if (ws_size >= need && batch >= 4096) {
        float*          tab  = (float*)d_ws;
        unsigned short* leaf = (unsigned short*)((char*)d_ws + tab_bytes);
        unsigned int*   prog = (unsigned int*)((char*)d_ws + tab_bytes + leaf_bytes);

        hipMemsetAsync(prog, 0, prog_bytes, stream);   // replay-safe reset

        softmax_rows_kernel<<<N_LEAVES, 64, 0, stream>>>(lp, tab);

        const int nunits = (batch + RPW - 1) / RPW;
        tree_pc_kernel<<<NBLK, TPB, 0, stream>>>(
            x, sf, st, (const f32x4*)tab, leaf, prog, (f32x4*)out,
            batch, nunits);
    } else {
        fused_kernel<<<(batch + 255) / 256, 256, 0, stream>>>(
            x, sf, st, lp, out, batch);
    }
}

// Round 11
// 169.707 us; speedup vs baseline: 15.0834x; 15.0834x over previous
//
#include <hip/hip_runtime.h>
#include <math.h>

#define INPUT_DIM 256
#define N_CLASSES 100
#define MAX_DEPTH 12
#define N_NODES   4095
#define N_LEAVES  4096

#define S_SEG  4                  // pipeline segments
#define TBLK   256                // traversal blocks (role: blockIdx < TBLK)
#define GBLK   256                // gather blocks
#define NBLK   (TBLK + GBLK)      // 512 blocks; 70 KB LDS -> 2 blocks/CU
#define TPB    512                // 8 waves
#define NWAVE  8
#define NPIPES (TBLK * NWAVE)     // 2048 traversal pipelines
#define RPW    3                  // rows per unit
#define TBUF   2                  // double buffer, prefetch distance 1
#define ROWP   260                // padded row stride (1040 B)
#define NF4    (N_CLASSES / 4)    // 25 f32x4 per output row

#define WAITV(N) asm volatile("s_waitcnt vmcnt(" #N ")" ::: "memory")
#define SCHEDB() __builtin_amdgcn_sched_barrier(0)

typedef float f32x4 __attribute__((ext_vector_type(4)));

__device__ __forceinline__ void async_load16(const void* gsrc, void* ldst) {
    __builtin_amdgcn_global_load_lds(
        (const __attribute__((address_space(1))) unsigned int*)gsrc,
        (__attribute__((address_space(3))) unsigned int*)ldst, 16, 0, 0);
}

// ---------------------------------------------------------------------------
// Kernel 1: row-softmax of leaf_probabilities [4096 x 100] -> tab
// ---------------------------------------------------------------------------
__global__ __launch_bounds__(64) void softmax_rows_kernel(
    const float* __restrict__ lp, float* __restrict__ tab) {
    const int row  = blockIdx.x;
    const int lane = threadIdx.x;
    const float* src = lp + (size_t)row * N_CLASSES;

    float v0 = src[lane];
    float v1 = (lane + 64 < N_CLASSES) ? src[lane + 64] : -INFINITY;

    float m = fmaxf(v0, v1);
    #pragma unroll
    for (int off = 32; off > 0; off >>= 1) m = fmaxf(m, __shfl_xor(m, off));

    float e0 = expf(v0 - m);
    float e1 = (lane + 64 < N_CLASSES) ? expf(v1 - m) : 0.0f;
    float s = e0 + e1;
    #pragma unroll
    for (int off = 32; off > 0; off >>= 1) s += __shfl_xor(s, off);

    const float inv = 1.0f / s;
    tab[(size_t)row * N_CLASSES + lane] = e0 * inv;
    if (lane + 64 < N_CLASSES)
        tab[(size_t)row * N_CLASSES + lane + 64] = e1 * inv;
}

// ---------------------------------------------------------------------------
// Kernel 2: pipelined step kernel. Roles by blockIdx:
//   blocks [0,256):   PURE-READ traversal of global units [u0,u1) — R8's
//     barrier-free wave-pipelines (3-row units, double-buffered DMA via
//     global_load_lds_dwordx4, per-wave counted vmcnt, 12-level LDS chain
//     with speculated children), leaf u16 -> global.
//   blocks [256,512): PURE-WRITE gather of out f32x4 range [j40,j41) from the
//     PREVIOUS segment (leaves complete at the prior kernel boundary — no
//     runtime handshake). Grid-stride, L2-resident tab, nontemporal stores.
// LDS 70.4 KB -> 2 blocks/CU: gather blocks co-reside with traversal blocks,
// so reads and writes flow concurrently machine-wide.
// ---------------------------------------------------------------------------
__global__ __launch_bounds__(TPB) void tree_step_kernel(
    const float* __restrict__ x,
    const float* __restrict__ split_features,
    const float* __restrict__ split_thresholds,
    const f32x4* __restrict__ tab4,
    unsigned short* __restrict__ leaf,
    f32x4* __restrict__ out4,
    int batch,
    int u0, int u1,        // traversal unit range (global units of RPW rows)
    int j40, int j41) {    // gather f32x4 range
    __shared__ float         s_rows[NWAVE][TBUF][RPW][ROWP];  // 49,920 B
    __shared__ float         s_thr[N_NODES];                  // 16,380 B
    __shared__ unsigned char s_feat[N_NODES + 1];             //  4,096 B

    const int tid  = threadIdx.x;
    const int wid  = tid >> 6;
    const int lane = tid & 63;

    if (blockIdx.x < TBLK) {
        // ========================= TRAVERSAL =========================
        for (int i = tid; i < N_NODES; i += TPB) {
            s_thr[i] = split_thresholds[i];
            int f = (int)floorf(split_features[i]);
            s_feat[i] = (unsigned char)min(max(f, 0), INPUT_DIM - 1);
        }
        __syncthreads();

        const int span = u1 - u0;
        const int pipe = blockIdx.x * NWAVE + wid;
        const int nk = (pipe < span) ? ((span - 1 - pipe) / NPIPES + 1) : 0;

        auto stage = [&](int k, int slot) {
            const long g = (long)u0 + pipe + (long)k * NPIPES;
            #pragma unroll
            for (int j = 0; j < RPW; ++j) {
                long r = g * RPW + j;
                if (r >= batch) r = batch - 1;      // valid dummy traffic
                const float* src = x + (size_t)r * INPUT_DIM + lane * 4;
                async_load16((const void*)src, (void*)&s_rows[wid][slot][j][0]);
            }
        };

        if (nk > 0) stage(0, 0);

        for (int k = 0; k < nk; ++k) {
            const bool more = (k + 1 < nk);
            if (more) stage(k + 1, (k + 1) & 1);    // prefetch distance 1
            SCHEDB();
            // drain unit k's 3 DMAs; newer ops stay in flight:
            // newer = leafstore(k-1)[1 if k>0] + stage(k+1)[3 if more]
            if (k == 0) { if (more) WAITV(3); else WAITV(0); }
            else       { if (more) WAITV(4); else WAITV(1); }
            SCHEDB();

            int leafv = 0;
            if (lane < RPW) {
                const float* row = &s_rows[wid][k & 1][lane][0];
                float t = s_thr[0];
                int   f = s_feat[0];
                int   n = 0;
                #pragma unroll
                for (int d = 0; d < MAX_DEPTH; ++d) {
                    const int l = 2 * n + 1;
                    if (d < MAX_DEPTH - 1) {
                        const float tl = s_thr[l],  tr = s_thr[l + 1];
                        const int   fl = s_feat[l], fr = s_feat[l + 1];
                        const int go = row[f] > t ? 1 : 0;  // 1 LDS gather/level
                        t = go ? tr : tl;
                        f = go ? fr : fl;
                        n = l + go;
                    } else {
                        n = l + (row[f] > t ? 1 : 0);
                    }
                }
                leafv = n - N_NODES;
            }

            const long rowbase = ((long)u0 + pipe + (long)k * NPIPES) * RPW;
            if (lane < RPW && rowbase + lane < batch)
                leaf[rowbase + lane] = (unsigned short)leafv;
        }
        WAITV(0);
    } else {
        // ========================= GATHER =========================
        const int gid = blockIdx.x - TBLK;
        for (int j = j40 + gid * TPB + tid; j < j41; j += GBLK * TPB) {
            const int r  = j / NF4;                 // magic-div by 25
            const int q  = j - r * NF4;
            const int lf = leaf[r];
            f32x4 v = tab4[(size_t)lf * NF4 + q];
            __builtin_nontemporal_store(v, &out4[j]);
        }
    }
}

// ---------------------------------------------------------------------------
// Fallback (ws too small / tiny batch): fully fused, per-thread softmax.
// ---------------------------------------------------------------------------
__global__ __launch_bounds__(256) void fused_kernel(
    const float* __restrict__ x,
    const float* __restrict__ split_features,
    const float* __restrict__ split_thresholds,
    const float* __restrict__ lp,
    float* __restrict__ out, int batch) {
    __shared__ float2 s_nodes[N_NODES];
    for (int i = threadIdx.x; i < N_NODES; i += blockDim.x) {
        int f = (int)floorf(split_features[i]);
        f = min(max(f, 0), INPUT_DIM - 1);
        float2 n; n.x = split_thresholds[i]; n.y = __int_as_float(f);
        s_nodes[i] = n;
    }
    __syncthreads();

    const int b = blockIdx.x * blockDim.x + threadIdx.x;
    if (b >= batch) return;

    const float* row = x + (size_t)b * INPUT_DIM;
    int node = 0;
    #pragma unroll
    for (int d = 0; d < MAX_DEPTH; ++d) {
        const float2 n = s_nodes[node];
        const float val = row[__float_as_int(n.y)];
        node = 2 * node + 1 + (val > n.x ? 1 : 0);
    }
    const int leaf = node - N_NODES;

    const float* src = lp + (size_t)leaf * N_CLASSES;
    float m = -INFINITY;
    for (int c = 0; c < N_CLASSES; ++c) m = fmaxf(m, src[c]);
    float s = 0.0f;
    float e[N_CLASSES];
    for (int c = 0; c < N_CLASSES; ++c) { e[c] = expf(src[c] - m); s += e[c]; }
    const float inv = 1.0f / s;
    float* dst = out + (size_t)b * N_CLASSES;
    for (int c = 0; c < N_CLASSES; ++c) dst[c] = e[c] * inv;
}

// ---------------------------------------------------------------------------
extern "C" void kernel_launch(void* const* d_in, const int* in_sizes, int n_in,
                              void* d_out, int out_size, void* d_ws, size_t ws_size,
                              hipStream_t stream) {
    const float* x  = (const float*)d_in[0];
    const float* sf = (const float*)d_in[1];
    const float* st = (const float*)d_in[2];
    const float* lp = (const float*)d_in[3];
    float* out = (float*)d_out;

    const int batch = in_sizes[0] / INPUT_DIM;

    const size_t tab_bytes  = (size_t)N_LEAVES * N_CLASSES * sizeof(float); // 1.6384 MB
    const size_t leaf_bytes = (size_t)batch * sizeof(unsigned short);
    const size_t need = tab_bytes + leaf_bytes;

    if (ws_size >= need && batch >= 4096) {
        float*          tab  = (float*)d_ws;
        unsigned short* leaf = (unsigned short*)((char*)d_ws + tab_bytes);

        softmax_rows_kernel<<<N_LEAVES, 64, 0, stream>>>(lp, tab);

        const int nunits = (batch + RPW - 1) / RPW;

        // segment boundaries: units ub[i], rows rb[i], f32x4 j4b[i]
        int ub[S_SEG + 1], j4b[S_SEG + 1];
        for (int i = 0; i <= S_SEG; ++i) {
            ub[i] = (int)((long)nunits * i / S_SEG);
            long rb = (long)ub[i] * RPW;
            if (rb > batch) rb = batch;
            j4b[i] = (int)(rb * NF4);
        }

        // steps: T(0) | T(1)||G(0) | ... | T(S-1)||G(S-2) | G(S-1)
        for (int t = 0; t <= S_SEG; ++t) {
            const int tu0 = (t < S_SEG) ? ub[t]     : 0;
            const int tu1 = (t < S_SEG) ? ub[t + 1] : 0;
            const int gj0 = (t > 0)     ? j4b[t - 1] : 0;
            const int gj1 = (t > 0)     ? j4b[t]     : 0;
            tree_step_kernel<<<NBLK, TPB, 0, stream>>>(
                x, sf, st, (const f32x4*)tab, leaf, (f32x4*)out,
                batch, tu0, tu1, gj0, gj1);
        }
    } else {
        fused_kernel<<<(batch + 255) / 256, 256, 0, stream>>>(
            x, sf, st, lp, out, batch);
    }
}

// Round 12
// 138.910 us; speedup vs baseline: 18.4274x; 1.2217x over previous
//
#include <hip/hip_runtime.h>
#include <math.h>

#define INPUT_DIM 256
#define N_CLASSES 100
#define MAX_DEPTH 12
#define N_NODES   4095
#define N_LEAVES  4096

#define TPB    512                // 8 waves
#define NWAVE  8
#define TBLK   512                // traverse blocks: 2/CU (70.4 KB LDS)
#define NPIPES (TBLK * NWAVE)     // 4096 pipelines
#define RPW    3                  // rows per unit
#define TBUF   2                  // double buffer, prefetch distance 1
#define ROWP   260                // padded row stride (1040 B)
#define NF4    (N_CLASSES / 4)    // 25 f32x4 per output row

#define WAITV(N) asm volatile("s_waitcnt vmcnt(" #N ")" ::: "memory")
#define SCHEDB() __builtin_amdgcn_sched_barrier(0)

typedef float f32x4 __attribute__((ext_vector_type(4)));

__device__ __forceinline__ void async_load16(const void* gsrc, void* ldst) {
    __builtin_amdgcn_global_load_lds(
        (const __attribute__((address_space(1))) unsigned int*)gsrc,
        (__attribute__((address_space(3))) unsigned int*)ldst, 16, 0, 0);
}

// ---------------------------------------------------------------------------
// Kernel 1: row-softmax of leaf_probabilities [4096 x 100] -> tab
// ---------------------------------------------------------------------------
__global__ __launch_bounds__(64) void softmax_rows_kernel(
    const float* __restrict__ lp, float* __restrict__ tab) {
    const int row  = blockIdx.x;
    const int lane = threadIdx.x;
    const float* src = lp + (size_t)row * N_CLASSES;

    float v0 = src[lane];
    float v1 = (lane + 64 < N_CLASSES) ? src[lane + 64] : -INFINITY;

    float m = fmaxf(v0, v1);
    #pragma unroll
    for (int off = 32; off > 0; off >>= 1) m = fmaxf(m, __shfl_xor(m, off));

    float e0 = expf(v0 - m);
    float e1 = (lane + 64 < N_CLASSES) ? expf(v1 - m) : 0.0f;
    float s = e0 + e1;
    #pragma unroll
    for (int off = 32; off > 0; off >>= 1) s += __shfl_xor(s, off);

    const float inv = 1.0f / s;
    tab[(size_t)row * N_CLASSES + lane] = e0 * inv;
    if (lane + 64 < N_CLASSES)
        tab[(size_t)row * N_CLASSES + lane + 64] = e1 * inv;
}

// ---------------------------------------------------------------------------
// Kernel 2: PURE-READ streamed traversal (serial-phase structure, R8).
// Barrier-free wave-pipelines; 3-row units double-buffered via
// global_load_lds_dwordx4; per-wave counted vmcnt (steady WAITV(4));
// 12-level LDS chain with speculated children; leaf u16 -> global.
// LDS: 8*2*3*1040 + 16380 + 4096 = 70,396 B -> 2 blocks/CU = 16 waves/CU
// (2x the outstanding-DMA streams of the 1-block/CU config).
// ---------------------------------------------------------------------------
__global__ __launch_bounds__(TPB) void traverse_kernel(
    const float* __restrict__ x,
    const float* __restrict__ split_features,
    const float* __restrict__ split_thresholds,
    unsigned short* __restrict__ leaf_out,
    int batch, int nunits) {
    __shared__ float         s_rows[NWAVE][TBUF][RPW][ROWP];  // 49,920 B
    __shared__ float         s_thr[N_NODES];                  // 16,380 B
    __shared__ unsigned char s_feat[N_NODES + 1];             //  4,096 B

    const int tid  = threadIdx.x;
    const int wid  = tid >> 6;
    const int lane = tid & 63;

    for (int i = tid; i < N_NODES; i += TPB) {
        s_thr[i] = split_thresholds[i];
        int f = (int)floorf(split_features[i]);
        s_feat[i] = (unsigned char)min(max(f, 0), INPUT_DIM - 1);
    }
    __syncthreads();          // only barrier in the kernel

    const int pipe = blockIdx.x * NWAVE + wid;
    const int nk = (pipe < nunits) ? ((nunits - 1 - pipe) / NPIPES + 1) : 0;

    auto stage = [&](int k, int slot) {
        const long g = (long)pipe + (long)k * NPIPES;
        #pragma unroll
        for (int j = 0; j < RPW; ++j) {
            long r = g * RPW + j;
            if (r >= batch) r = batch - 1;          // valid dummy traffic
            const float* src = x + (size_t)r * INPUT_DIM + lane * 4;
            async_load16((const void*)src, (void*)&s_rows[wid][slot][j][0]);
        }
    };

    if (nk > 0) stage(0, 0);

    for (int k = 0; k < nk; ++k) {
        const bool more = (k + 1 < nk);
        if (more) stage(k + 1, (k + 1) & 1);        // prefetch distance 1
        SCHEDB();
        // queue (oldest->newest): stage(k)[3], leafstore(k-1)[1 if k>0],
        // stage(k+1)[3 if more]. Drain stage(k) only:
        if (k == 0) { if (more) WAITV(3); else WAITV(0); }
        else        { if (more) WAITV(4); else WAITV(1); }
        SCHEDB();

        int leafv = 0;
        if (lane < RPW) {
            const float* row = &s_rows[wid][k & 1][lane][0];
            float t = s_thr[0];
            int   f = s_feat[0];
            int   n = 0;
            #pragma unroll
            for (int d = 0; d < MAX_DEPTH; ++d) {
                const int l = 2 * n + 1;
                if (d < MAX_DEPTH - 1) {
                    const float tl = s_thr[l],  tr = s_thr[l + 1];
                    const int   fl = s_feat[l], fr = s_feat[l + 1];
                    const int go = row[f] > t ? 1 : 0;   // 1 LDS gather/level
                    t = go ? tr : tl;
                    f = go ? fr : fl;
                    n = l + go;
                } else {
                    n = l + (row[f] > t ? 1 : 0);
                }
            }
            leafv = n - N_NODES;
        }

        const long rowbase = ((long)pipe + (long)k * NPIPES) * RPW;
        if (lane < RPW && rowbase + lane < batch)
            leaf_out[rowbase + lane] = (unsigned short)leafv;
    }
    WAITV(0);
}

// ---------------------------------------------------------------------------
// Kernel 3: PURE-WRITE gather. out4[j] = tab4[leaf[j/25]*25 + j%25].
// Grid-stride thread-per-f32x4; leaf u16 L1/L2-hot, tab L2-resident,
// coalesced nontemporal stores.
// ---------------------------------------------------------------------------
__global__ __launch_bounds__(256) void gather_out_kernel(
    const f32x4* __restrict__ tab4,
    const unsigned short* __restrict__ leaf,
    f32x4* __restrict__ out4, int total4) {
    for (int j = blockIdx.x * 256 + threadIdx.x; j < total4;
         j += gridDim.x * 256) {
        const int r = j / NF4;                 // magic-div by 25
        const int q = j - r * NF4;
        const int lf = leaf[r];
        f32x4 v = tab4[(size_t)lf * NF4 + q];
        __builtin_nontemporal_store(v, &out4[j]);
    }
}

// ---------------------------------------------------------------------------
// Fallback (ws too small / tiny batch): fully fused, per-thread softmax.
// ---------------------------------------------------------------------------
__global__ __launch_bounds__(256) void fused_kernel(
    const float* __restrict__ x,
    const float* __restrict__ split_features,
    const float* __restrict__ split_thresholds,
    const float* __restrict__ lp,
    float* __restrict__ out, int batch) {
    __shared__ float2 s_nodes[N_NODES];
    for (int i = threadIdx.x; i < N_NODES; i += blockDim.x) {
        int f = (int)floorf(split_features[i]);
        f = min(max(f, 0), INPUT_DIM - 1);
        float2 n; n.x = split_thresholds[i]; n.y = __int_as_float(f);
        s_nodes[i] = n;
    }
    __syncthreads();

    const int b = blockIdx.x * blockDim.x + threadIdx.x;
    if (b >= batch) return;

    const float* row = x + (size_t)b * INPUT_DIM;
    int node = 0;
    #pragma unroll
    for (int d = 0; d < MAX_DEPTH; ++d) {
        const float2 n = s_nodes[node];
        const float val = row[__float_as_int(n.y)];
        node = 2 * node + 1 + (val > n.x ? 1 : 0);
    }
    const int leaf = node - N_NODES;

    const float* src = lp + (size_t)leaf * N_CLASSES;
    float m = -INFINITY;
    for (int c = 0; c < N_CLASSES; ++c) m = fmaxf(m, src[c]);
    float s = 0.0f;
    float e[N_CLASSES];
    for (int c = 0; c < N_CLASSES; ++c) { e[c] = expf(src[c] - m); s += e[c]; }
    const float inv = 1.0f / s;
    float* dst = out + (size_t)b * N_CLASSES;
    for (int c = 0; c < N_CLASSES; ++c) dst[c] = e[c] * inv;
}

// ---------------------------------------------------------------------------
extern "C" void kernel_launch(void* const* d_in, const int* in_sizes, int n_in,
                              void* d_out, int out_size, void* d_ws, size_t ws_size,
                              hipStream_t stream) {
    const float* x  = (const float*)d_in[0];
    const float* sf = (const float*)d_in[1];
    const float* st = (const float*)d_in[2];
    const float* lp = (const float*)d_in[3];
    float* out = (float*)d_out;

    const int batch = in_sizes[0] / INPUT_DIM;

    const size_t tab_bytes = (size_t)N_LEAVES * N_CLASSES * sizeof(float); // 1.6384 MB
    const size_t need = tab_bytes + (size_t)batch * sizeof(unsigned short);

    if (ws_size >= need && batch >= 4096) {
        float* tab = (float*)d_ws;
        unsigned short* leaf = (unsigned short*)((char*)d_ws + tab_bytes);

        softmax_rows_kernel<<<N_LEAVES, 64, 0, stream>>>(lp, tab);

        const int nunits = (batch + RPW - 1) / RPW;
        int nblk = (nunits + NWAVE - 1) / NWAVE;
        if (nblk > TBLK) nblk = TBLK;
        traverse_kernel<<<nblk, TPB, 0, stream>>>(
            x, sf, st, leaf, batch, nunits);

        const int total4 = batch * NF4;
        int nb2 = (total4 + 255) / 256;
        if (nb2 > 2048) nb2 = 2048;
        gather_out_kernel<<<nb2, 256, 0, stream>>>(
            (const f32x4*)tab, leaf, (f32x4*)out, total4);
    } else {
        fused_kernel<<<(batch + 255) / 256, 256, 0, stream>>>(
            x, sf, st, lp, out, batch);
    }
}